// Round 8
// baseline (692223.486 us; speedup 1.0000x reference)
//
#include <hip/hip_runtime.h>
#include <cstdint>
#include <cstddef>

#define NB 256
#define NT 512

// Tsit5 tableau (Tsitouras 2011); compile-time double->f32 rounding matches
// jax weak-type scalar->f32 casts.
__constant__ float c_A[6][5] = {
  {0.f, 0.f, 0.f, 0.f, 0.f},
  {0.161f, 0.f, 0.f, 0.f, 0.f},
  {-0.008480655492356989f, 0.335480655492357f, 0.f, 0.f, 0.f},
  {2.8971530571054935f, -6.359448489975075f, 4.3622954328695815f, 0.f, 0.f},
  {5.325864828439257f, -11.748883564062828f, 7.4955393428898365f, -0.09249506636175525f, 0.f},
  {5.86145544294642f, -12.92096931784711f, 8.159367898576159f, -0.071584973281401f, -0.028269050394068383f}
};
__constant__ float c_B[6] = {
  0.09646076681806523f, 0.01f, 0.4798896504144996f,
  1.379008574103742f, -3.290069515436081f, 2.324710524099774f
};

// Agent-scope accesses for cross-block activation traffic: served at the
// coherence point (bypass non-coherent per-XCD L1/L2). Weights use normal
// cacheable loads (read-only, cannot go stale).
__device__ __forceinline__ float ld_dev(const float* p) {
  return __hip_atomic_load(const_cast<float*>(p), __ATOMIC_RELAXED, __HIP_MEMORY_SCOPE_AGENT);
}
__device__ __forceinline__ void st_dev(float* p, float v) {
  __hip_atomic_store(p, v, __ATOMIC_RELAXED, __HIP_MEMORY_SCOPE_AGENT);
}

// Two-level grid barrier: 16 groups x 16 blocks, monotonic counters (ws region
// zeroed each launch). Pure spin poll (no s_sleep): poll RTT ~250ns is the
// wake-latency floor; 256 spinners on one L3 line is < 1 GB/s of traffic.
__device__ __forceinline__ void gbar(unsigned* bar, unsigned ph) {
  __syncthreads();   // all threads' sc-stores drained before arrival
  if (threadIdx.x == 0) {
    const unsigned grp = blockIdx.x >> 4;
    unsigned old = __hip_atomic_fetch_add(&bar[grp * 32], 1u, __ATOMIC_ACQ_REL, __HIP_MEMORY_SCOPE_AGENT);
    if (old == ph * 16u - 1u) {                 // last of my group
      unsigned r = __hip_atomic_fetch_add(&bar[512], 1u, __ATOMIC_ACQ_REL, __HIP_MEMORY_SCOPE_AGENT);
      if (r == ph * 16u - 1u) {                 // last group overall
        __hip_atomic_store(&bar[544], ph, __ATOMIC_RELEASE, __HIP_MEMORY_SCOPE_AGENT);
      }
    }
    while (__hip_atomic_load(&bar[544], __ATOMIC_ACQUIRE, __HIP_MEMORY_SCOPE_AGENT) < ph) { }
  }
  __syncthreads();
}

__device__ __forceinline__ float wred(float v) {
#pragma unroll
  for (int off = 32; off > 0; off >>= 1) v += __shfl_xor(v, off, 64);
  return v;
}

__device__ __forceinline__ float dot4(float4 a, float4 b) {
  return a.x * b.x + a.y * b.y + a.z * b.z + a.w * b.w;
}

__global__ __launch_bounds__(NT, 2) void ode_kernel(
    const float* __restrict__ z0,
    const float* __restrict__ W1, const float* __restrict__ b1,
    const float* __restrict__ W2, const float* __restrict__ b2,
    const float* __restrict__ W3, const float* __restrict__ b3,
    const int* __restrict__ t0p, const int* __restrict__ t1p,
    const int* __restrict__ nsp,
    float* __restrict__ traj, float* ws)
{
  __shared__ float lds_v[4096];
  __shared__ float lds_part[4][2];

  const int tid = threadIdx.x;
  const int bid = blockIdx.x;
  const int wv  = tid >> 6;   // wave id 0..7
  const int ln  = tid & 63;

  unsigned* bar = (unsigned*)ws;        // bytes [0, 2180) used; memset 4096
  float* y  = ws + 1024;                // 1024
  float* kk = y  + 1024;                // 5 * 1024 (k1..k5; k6 never shared)
  float* h1 = kk + 6 * 1024;            // 4096
  float* h2 = h1 + 4096;                // 4096

  const int   ns = nsp[0];
  const float dt = (float)(t1p[0] - t0p[0]) / (float)ns;

  // ---- weight preload: 2 rows of W1 + 2 rows of W2 per wave, in registers.
  // Static indexing throughout (full unroll) so these stay in VGPRs.
  const int r0 = bid * 16 + wv * 2;     // my W1/W2 row pair
  float4 w1a[4], w1b[4];
  {
    const float4* pa = (const float4*)(W1 + (size_t)r0 * 1024);
    const float4* pb = pa + 256;
#pragma unroll
    for (int j = 0; j < 4; ++j) { w1a[j] = pa[ln + 64 * j]; w1b[j] = pb[ln + 64 * j]; }
  }
  float4 w2a[16], w2b[16];
  {
    const float4* pa = (const float4*)(W2 + (size_t)r0 * 4096);
    const float4* pb = pa + 1024;
#pragma unroll
    for (int j = 0; j < 16; ++j) { w2a[j] = pa[ln + 64 * j]; w2b[j] = pb[ln + 64 * j]; }
  }
  const float b1a = b1[r0], b1bv = b1[r0 + 1];
  const float b2a = b2[r0], b2bv = b2[r0 + 1];

  unsigned ph = 1;

  // init: y = z0, traj[0] = z0  (each block owns 4 components)
  if (tid < 4) {
    int c = bid * 4 + tid;
    float v = z0[c];
    st_dev(y + c, v);
    traj[c] = v;
  }
  gbar(bar, ph); ph++;

  for (int n = 1; n < ns; ++n) {
    for (int e = 0; e < 6; ++e) {
      // ---------- stage A: z = y + dt*sum_j A[e][j]*k_j ; h1 = tanh(W1 z + b1)
#pragma unroll 2
      for (int half = 0; half < 2; ++half) {
        int c = tid + half * NT;
        float acc = 0.f;
        for (int j = 0; j < e; ++j)
          acc += c_A[e][j] * ld_dev(kk + j * 1024 + c);
        lds_v[c] = ld_dev(y + c) + dt * acc;
      }
      __syncthreads();
      {
        const float4* zp = (const float4*)lds_v;
        float s0 = 0.f, s1 = 0.f;
#pragma unroll
        for (int j = 0; j < 4; ++j) {
          float4 z4 = zp[ln + 64 * j];
          s0 += dot4(w1a[j], z4);
          s1 += dot4(w1b[j], z4);
        }
        s0 = wred(s0); s1 = wred(s1);
        if (ln == 0) {
          st_dev(h1 + r0,     tanhf(s0 + b1a));
          st_dev(h1 + r0 + 1, tanhf(s1 + b1bv));
        }
      }
      gbar(bar, ph); ph++;

      // ---------- stage B: h2 = tanh(W2 h1 + b2)
#pragma unroll
      for (int m = 0; m < 8; ++m)
        lds_v[tid + NT * m] = ld_dev(h1 + tid + NT * m);
      __syncthreads();
      {
        const float4* zp = (const float4*)lds_v;
        float s0 = 0.f, s1 = 0.f;
#pragma unroll
        for (int j = 0; j < 16; ++j) {
          float4 z4 = zp[ln + 64 * j];
          s0 += dot4(w2a[j], z4);
          s1 += dot4(w2b[j], z4);
        }
        s0 = wred(s0); s1 = wred(s1);
        if (ln == 0) {
          st_dev(h2 + r0,     tanhf(s0 + b2a));
          st_dev(h2 + r0 + 1, tanhf(s1 + b2bv));
        }
      }
      gbar(bar, ph); ph++;

      // ---------- stage C: k_e = W3 h2 + b3 ; (e==5) y update + traj store
      // W3 stays on cached loads: per-XCD footprint = 32 blocks x 64KB = 2MB,
      // L2-resident now that W1/W2 never touch L2 after the prologue.
#pragma unroll
      for (int m = 0; m < 8; ++m)
        lds_v[tid + NT * m] = ld_dev(h2 + tid + NT * m);
      __syncthreads();
      {
        int q  = wv >> 1;                  // row within block (4 rows/block)
        int hh = wv & 1;                   // K-half
        int r  = bid * 4 + q;
        const float4* wp = (const float4*)(W3 + (size_t)r * 4096);
        const float4* zp = (const float4*)lds_v;
        float s = 0.f;
#pragma unroll
        for (int j = 0; j < 8; ++j) {
          int idx = hh * 512 + ln + 64 * j;
          s += dot4(wp[idx], zp[idx]);
        }
        s = wred(s);
        if (ln == 0) lds_part[q][hh] = s;
      }
      __syncthreads();
      if (tid < 4) {
        int q = tid;
        int r = bid * 4 + q;
        float kv = lds_part[q][0] + lds_part[q][1] + b3[r];
        if (e < 5) {
          st_dev(kk + e * 1024 + r, kv);
        } else {
          float s = c_B[0] * ld_dev(kk + r);
          s += c_B[1] * ld_dev(kk + 1024 + r);
          s += c_B[2] * ld_dev(kk + 2048 + r);
          s += c_B[3] * ld_dev(kk + 3072 + r);
          s += c_B[4] * ld_dev(kk + 4096 + r);
          s += c_B[5] * kv;
          float yn = ld_dev(y + r) + dt * s;
          st_dev(y + r, yn);
          traj[(size_t)n * 1024 + r] = yn;   // plain store: d_out read after sync
        }
      }
      gbar(bar, ph); ph++;
    }
  }
}

extern "C" void kernel_launch(void* const* d_in, const int* in_sizes, int n_in,
                              void* d_out, int out_size, void* d_ws, size_t ws_size,
                              hipStream_t stream) {
  const float* z0 = (const float*)d_in[0];
  const float* W1 = (const float*)d_in[1];
  const float* b1 = (const float*)d_in[2];
  const float* W2 = (const float*)d_in[3];
  const float* b2 = (const float*)d_in[4];
  const float* W3 = (const float*)d_in[5];
  const float* b3 = (const float*)d_in[6];
  const int* t0 = (const int*)d_in[7];
  const int* t1 = (const int*)d_in[8];
  const int* ns = (const int*)d_in[9];
  float* traj = (float*)d_out;

  // barrier region is monotonic counters — must start at 0 every launch
  hipMemsetAsync(d_ws, 0, 4096, stream);
  ode_kernel<<<NB, NT, 0, stream>>>(z0, W1, b1, W2, b2, W3, b3, t0, t1, ns,
                                    traj, (float*)d_ws);
}

// Round 9
// 425533.789 us; speedup vs baseline: 1.6267x; 1.6267x over previous
//
#include <hip/hip_runtime.h>
#include <cstdint>
#include <cstddef>

#define NB 256
#define NT 1024

// Tsit5 tableau (Tsitouras 2011). c_A[e][j] = coeff of k_{j+1} in input of eval e.
__constant__ float c_A[6][5] = {
  {0.f, 0.f, 0.f, 0.f, 0.f},
  {0.161f, 0.f, 0.f, 0.f, 0.f},
  {-0.008480655492356989f, 0.335480655492357f, 0.f, 0.f, 0.f},
  {2.8971530571054935f, -6.359448489975075f, 4.3622954328695815f, 0.f, 0.f},
  {5.325864828439257f, -11.748883564062828f, 7.4955393428898365f, -0.09249506636175525f, 0.f},
  {5.86145544294642f, -12.92096931784711f, 8.159367898576159f, -0.071584973281401f, -0.028269050394068383f}
};
__constant__ float c_B[6] = {
  0.09646076681806523f, 0.01f, 0.4798896504144996f,
  1.379008574103742f, -3.290069515436081f, 2.324710524099774f
};

// Agent-scope RELAXED accesses for cross-block activation traffic: served at
// the coherence point (bypass non-coherent per-XCD L1/L2), no invalidations.
__device__ __forceinline__ float ld_dev(const float* p) {
  return __hip_atomic_load(const_cast<float*>(p), __ATOMIC_RELAXED, __HIP_MEMORY_SCOPE_AGENT);
}
__device__ __forceinline__ void st_dev(float* p, float v) {
  __hip_atomic_store(p, v, __ATOMIC_RELAXED, __HIP_MEMORY_SCOPE_AGENT);
}

// Two-level grid barrier, hierarchical release.
// Layout (u32 indices into ws): arrival[g] @ g*32 (g<16), root @ 512,
// release flag[g] @ 768+g*32. All on distinct 128B lines; memset 8192 B.
// Spin is RELAXED (no per-poll invalidation); one ACQUIRE load on exit.
// 16 spinners per flag line (was 256 on one line).
__device__ __forceinline__ void gbar(unsigned* bar, unsigned ph) {
  __syncthreads();   // drains this block's vm stores before arrival
  if (threadIdx.x == 0) {
    const unsigned grp = blockIdx.x >> 4;
    unsigned old = __hip_atomic_fetch_add(&bar[grp * 32], 1u, __ATOMIC_ACQ_REL, __HIP_MEMORY_SCOPE_AGENT);
    if (old == ph * 16u - 1u) {                 // last of my 16-block group
      unsigned r = __hip_atomic_fetch_add(&bar[512], 1u, __ATOMIC_ACQ_REL, __HIP_MEMORY_SCOPE_AGENT);
      if (r == ph * 16u - 1u) {                 // last group overall
#pragma unroll
        for (int g = 0; g < 16; ++g)
          __hip_atomic_store(&bar[768 + g * 32], ph, __ATOMIC_RELEASE, __HIP_MEMORY_SCOPE_AGENT);
      }
    }
    while (__hip_atomic_load(&bar[768 + grp * 32], __ATOMIC_RELAXED, __HIP_MEMORY_SCOPE_AGENT) < ph) { }
    (void)__hip_atomic_load(&bar[768 + grp * 32], __ATOMIC_ACQUIRE, __HIP_MEMORY_SCOPE_AGENT);
  }
  __syncthreads();
}

__device__ __forceinline__ float wred(float v) {
#pragma unroll
  for (int off = 32; off > 0; off >>= 1) v += __shfl_xor(v, off, 64);
  return v;
}

__device__ __forceinline__ float dot4(float4 a, float4 b) {
  return a.x * b.x + a.y * b.y + a.z * b.z + a.w * b.w;
}

// 1024 thr = 16 waves/block, 1 block/CU. Weight budget/lane: W1 row 16 VGPR +
// W2 row 64 VGPR = 80; ~120 peak < 128 cap (either launch_bounds semantics).
__global__ __launch_bounds__(NT, 1) void ode_kernel(
    const float* __restrict__ z0,
    const float* __restrict__ W1, const float* __restrict__ b1,
    const float* __restrict__ W2, const float* __restrict__ b2,
    const float* __restrict__ W3, const float* __restrict__ b3,
    const int* __restrict__ t0p, const int* __restrict__ t1p,
    const int* __restrict__ nsp,
    float* __restrict__ traj, float* ws)
{
  __shared__ float w3s[4 * 4096];     // this block's 4 W3 rows (64 KB)
  __shared__ float lds_v[4096];       // staged activation vector
  __shared__ float kh[6][4];          // k-history for owned components
  __shared__ float ylds[4];           // owned y components
  __shared__ float lds_part[4][4];

  const int tid = threadIdx.x;
  const int bid = blockIdx.x;
  const int wv  = tid >> 6;           // wave 0..15
  const int ln  = tid & 63;

  unsigned* bar = (unsigned*)ws;      // bytes [0, 8192) barrier region (memset)
  float* zin = ws + 2048;             // 1024: pre-combined eval input
  float* h1g = ws + 3072;             // 4096
  float* h2g = ws + 7168;             // 4096

  const int   ns = nsp[0];
  const float dt = (float)(t1p[0] - t0p[0]) / (float)ns;

  // ---- register-resident weights: 1 row W1 + 1 row W2 per wave
  const int r0 = bid * 16 + wv;
  float4 w1[4];
  {
    const float4* p1 = (const float4*)(W1 + (size_t)r0 * 1024);
#pragma unroll
    for (int j = 0; j < 4; ++j) w1[j] = p1[ln + 64 * j];
  }
  float4 w2[16];
  {
    const float4* p2 = (const float4*)(W2 + (size_t)r0 * 4096);
#pragma unroll
    for (int j = 0; j < 16; ++j) w2[j] = p2[ln + 64 * j];
  }
  const float b1r = b1[r0];
  const float b2r = b2[r0];

  // ---- W3 rows into LDS (once)
  {
    const float4* p3 = (const float4*)(W3 + (size_t)bid * 4 * 4096);
    float4* d = (float4*)w3s;
#pragma unroll
    for (int m = 0; m < 4; ++m) d[tid + 1024 * m] = p3[tid + 1024 * m];
  }

  unsigned ph = 1;

  if (tid < 4) {
    int c = bid * 4 + tid;
    float v = z0[c];
    ylds[tid] = v;
    st_dev(zin + c, v);               // eval-0 input is y itself
    traj[c] = v;
  }
  gbar(bar, ph); ph++;

  for (int n = 1; n < ns; ++n) {
    for (int e = 0; e < 6; ++e) {
      // ---------- stage A: h1 = tanh(W1 * zin + b1)   (zin pre-combined)
      lds_v[tid] = ld_dev(zin + tid);
      __syncthreads();
      {
        const float4* zp = (const float4*)lds_v;
        float s = 0.f;
#pragma unroll
        for (int j = 0; j < 4; ++j) s += dot4(w1[j], zp[ln + 64 * j]);
        s = wred(s);
        if (ln == 0) st_dev(h1g + r0, tanhf(s + b1r));
      }
      gbar(bar, ph); ph++;

      // ---------- stage B: h2 = tanh(W2 * h1 + b2)
#pragma unroll
      for (int m = 0; m < 4; ++m)
        lds_v[tid + 1024 * m] = ld_dev(h1g + tid + 1024 * m);
      __syncthreads();
      {
        const float4* zp = (const float4*)lds_v;
        float s = 0.f;
#pragma unroll
        for (int j = 0; j < 16; ++j) s += dot4(w2[j], zp[ln + 64 * j]);
        s = wred(s);
        if (ln == 0) st_dev(h2g + r0, tanhf(s + b2r));
      }
      gbar(bar, ph); ph++;

      // ---------- stage C: k_e = W3 * h2 + b3 (4 owned comps); pre-combine
      // next eval's zin (or final y update + traj at e==5)
#pragma unroll
      for (int m = 0; m < 4; ++m)
        lds_v[tid + 1024 * m] = ld_dev(h2g + tid + 1024 * m);
      __syncthreads();
      {
        int q  = wv >> 2;               // owned row 0..3
        int kq = wv & 3;                // K-quarter
        const float4* wp = (const float4*)w3s + q * 1024 + kq * 256;
        const float4* zp = (const float4*)lds_v + kq * 256;
        float s = 0.f;
#pragma unroll
        for (int j = 0; j < 4; ++j) s += dot4(wp[ln + 64 * j], zp[ln + 64 * j]);
        s = wred(s);
        if (ln == 0) lds_part[q][kq] = s;
      }
      __syncthreads();
      if (tid < 4) {
        int c = bid * 4 + tid;
        float kv = lds_part[tid][0] + lds_part[tid][1] + lds_part[tid][2] +
                   lds_part[tid][3] + b3[c];
        kh[e][tid] = kv;
        float z;
        if (e < 5) {
          // zin_{e+1} = y + dt * sum_{j<=e} A[e+1][j] * k_j
          float acc = 0.f;
          for (int j = 0; j <= e; ++j) acc += c_A[e + 1][j] * kh[j][tid];
          z = ylds[tid] + dt * acc;
        } else {
          float acc = c_B[0] * kh[0][tid] + c_B[1] * kh[1][tid]
                    + c_B[2] * kh[2][tid] + c_B[3] * kh[3][tid]
                    + c_B[4] * kh[4][tid] + c_B[5] * kv;
          z = ylds[tid] + dt * acc;     // y_{n+1}; also eval-0 input of step n+1
          ylds[tid] = z;
          traj[(size_t)n * 1024 + c] = z;
        }
        st_dev(zin + c, z);
      }
      gbar(bar, ph); ph++;
    }
  }
}

extern "C" void kernel_launch(void* const* d_in, const int* in_sizes, int n_in,
                              void* d_out, int out_size, void* d_ws, size_t ws_size,
                              hipStream_t stream) {
  const float* z0 = (const float*)d_in[0];
  const float* W1 = (const float*)d_in[1];
  const float* b1 = (const float*)d_in[2];
  const float* W2 = (const float*)d_in[3];
  const float* b2 = (const float*)d_in[4];
  const float* W3 = (const float*)d_in[5];
  const float* b3 = (const float*)d_in[6];
  const int* t0 = (const int*)d_in[7];
  const int* t1 = (const int*)d_in[8];
  const int* ns = (const int*)d_in[9];
  float* traj = (float*)d_out;

  // barrier counters/flags are monotonic — must start at 0 every launch
  hipMemsetAsync(d_ws, 0, 8192, stream);
  ode_kernel<<<NB, NT, 0, stream>>>(z0, W1, b1, W2, b2, W3, b3, t0, t1, ns,
                                    traj, (float*)d_ws);
}

// Round 10
// 349807.593 us; speedup vs baseline: 1.9789x; 1.2165x over previous
//
#include <hip/hip_runtime.h>
#include <cstdint>
#include <cstddef>

#define NB 256
#define NT 1024

// Tsit5 tableau (Tsitouras 2011). c_A[e][j] = coeff of k_{j+1} in input of eval e.
__constant__ float c_A[6][5] = {
  {0.f, 0.f, 0.f, 0.f, 0.f},
  {0.161f, 0.f, 0.f, 0.f, 0.f},
  {-0.008480655492356989f, 0.335480655492357f, 0.f, 0.f, 0.f},
  {2.8971530571054935f, -6.359448489975075f, 4.3622954328695815f, 0.f, 0.f},
  {5.325864828439257f, -11.748883564062828f, 7.4955393428898365f, -0.09249506636175525f, 0.f},
  {5.86145544294642f, -12.92096931784711f, 8.159367898576159f, -0.071584973281401f, -0.028269050394068383f}
};
__constant__ float c_B[6] = {
  0.09646076681806523f, 0.01f, 0.4798896504144996f,
  1.379008574103742f, -3.290069515436081f, 2.324710524099774f
};

// Data path: agent-scope RELAXED = sc-bypass loads/stores, always served at
// the coherence point (L3). Never cached in L1/L2 -> nothing can go stale ->
// no acquire fences needed anywhere in this kernel.
__device__ __forceinline__ float ld_dev(const float* p) {
  return __hip_atomic_load(const_cast<float*>(p), __ATOMIC_RELAXED, __HIP_MEMORY_SCOPE_AGENT);
}
__device__ __forceinline__ void st_dev(float* p, float v) {
  __hip_atomic_store(p, v, __ATOMIC_RELAXED, __HIP_MEMORY_SCOPE_AGENT);
}

// Two-level grid barrier, ALL-RELAXED arrivals/polls (no acquire -> no L1/L2
// invalidation storms; that acq/rel traffic is the prime suspect for r9's
// 12us/stage). Ordering argument: __syncthreads() drains vmcnt(0), so every
// block's sc-stores are ACKED at L3 before its arrival add ISSUES; the root's
// flag store is RELEASE (cheap waitcnt, no invalidate); consumers poll
// RELAXED (sc-bypass = always fresh) and their subsequent data loads are
// sc-bypass too. Monotonic counters; ws[0,8192) memset each launch.
__device__ __forceinline__ void gbar(unsigned* bar, unsigned ph) {
  __syncthreads();   // drains this block's sc-stores (vmcnt(0)) before arrival
  if (threadIdx.x == 0) {
    const unsigned grp = blockIdx.x >> 4;
    unsigned old = __hip_atomic_fetch_add(&bar[grp * 32], 1u, __ATOMIC_RELAXED, __HIP_MEMORY_SCOPE_AGENT);
    if (old == ph * 16u - 1u) {                 // last of my 16-block group
      unsigned r = __hip_atomic_fetch_add(&bar[512], 1u, __ATOMIC_RELAXED, __HIP_MEMORY_SCOPE_AGENT);
      if (r == ph * 16u - 1u) {                 // last group overall
#pragma unroll
        for (int g = 0; g < 16; ++g)
          __hip_atomic_store(&bar[768 + g * 32], ph, __ATOMIC_RELEASE, __HIP_MEMORY_SCOPE_AGENT);
      }
    }
    while (__hip_atomic_load(&bar[768 + grp * 32], __ATOMIC_RELAXED, __HIP_MEMORY_SCOPE_AGENT) < ph) { }
  }
  __syncthreads();
}

__device__ __forceinline__ float wred(float v) {
#pragma unroll
  for (int off = 32; off > 0; off >>= 1) v += __shfl_xor(v, off, 64);
  return v;
}

__device__ __forceinline__ float dot4(float4 a, float4 b) {
  return a.x * b.x + a.y * b.y + a.z * b.z + a.w * b.w;
}

// 16 waves/block, 1 block/CU (grid=256=CUs). Weights: W2 row in regs
// (64 VGPR/lane; unified file may park it in AGPRs), W1+W3 rows in LDS.
// waves_per_eu(4,4): exactly 4 waves/EU -> full 128-VGPR budget, no
// occupancy-heuristic clamping.
__global__
__attribute__((amdgpu_flat_work_group_size(NT, NT), amdgpu_waves_per_eu(4, 4)))
void ode_kernel(
    const float* __restrict__ z0,
    const float* __restrict__ W1, const float* __restrict__ b1,
    const float* __restrict__ W2, const float* __restrict__ b2,
    const float* __restrict__ W3, const float* __restrict__ b3,
    const int* __restrict__ t0p, const int* __restrict__ t1p,
    const int* __restrict__ nsp,
    float* __restrict__ traj, float* ws)
{
  __shared__ float w3s[4 * 4096];     // this block's 4 W3 rows   (64 KB)
  __shared__ float w1s[16 * 1024];    // this block's 16 W1 rows  (64 KB)
  __shared__ float lds_v[4096];       // staged activation vector (16 KB)
  __shared__ float kh[6][4];          // k-history for owned components
  __shared__ float ylds[4];           // owned y components
  __shared__ float lds_part[4][4];

  const int tid = threadIdx.x;
  const int bid = blockIdx.x;
  const int wv  = tid >> 6;           // wave 0..15
  const int ln  = tid & 63;

  unsigned* bar = (unsigned*)ws;      // bytes [0, 8192) barrier region (memset)
  float* zin = ws + 2048;             // 1024: pre-combined eval input
  float* h1g = ws + 3072;             // 4096
  float* h2g = ws + 7168;             // 4096

  const int   ns = nsp[0];
  const float dt = (float)(t1p[0] - t0p[0]) / (float)ns;

  // ---- register-resident W2: 1 row per wave
  const int r0 = bid * 16 + wv;
  float4 w2[16];
  {
    const float4* p2 = (const float4*)(W2 + (size_t)r0 * 4096);
#pragma unroll
    for (int j = 0; j < 16; ++j) w2[j] = p2[ln + 64 * j];
  }
  const float b1r = b1[r0];
  const float b2r = b2[r0];

  // ---- W1 + W3 rows into LDS (once)
  {
    const float4* p1 = (const float4*)(W1 + (size_t)bid * 16 * 1024);
    float4* d1 = (float4*)w1s;
#pragma unroll
    for (int m = 0; m < 4; ++m) d1[tid + 1024 * m] = p1[tid + 1024 * m];
    const float4* p3 = (const float4*)(W3 + (size_t)bid * 4 * 4096);
    float4* d3 = (float4*)w3s;
#pragma unroll
    for (int m = 0; m < 4; ++m) d3[tid + 1024 * m] = p3[tid + 1024 * m];
  }

  unsigned ph = 1;

  if (tid < 4) {
    int c = bid * 4 + tid;
    float v = z0[c];
    ylds[tid] = v;
    st_dev(zin + c, v);               // eval-0 input is y itself
    traj[c] = v;
  }
  gbar(bar, ph); ph++;

  for (int n = 1; n < ns; ++n) {
    for (int e = 0; e < 6; ++e) {
      // ---------- stage A: h1 = tanh(W1 * zin + b1)   (zin pre-combined)
      lds_v[tid] = ld_dev(zin + tid);
      __syncthreads();
      {
        const float4* zp = (const float4*)lds_v;
        const float4* wp = (const float4*)w1s + wv * 256;
        float s = 0.f;
#pragma unroll
        for (int j = 0; j < 4; ++j) s += dot4(wp[ln + 64 * j], zp[ln + 64 * j]);
        s = wred(s);
        if (ln == 0) st_dev(h1g + r0, tanhf(s + b1r));
      }
      gbar(bar, ph); ph++;

      // ---------- stage B: h2 = tanh(W2 * h1 + b2)
#pragma unroll
      for (int m = 0; m < 4; ++m)
        lds_v[tid + 1024 * m] = ld_dev(h1g + tid + 1024 * m);
      __syncthreads();
      {
        const float4* zp = (const float4*)lds_v;
        float s = 0.f;
#pragma unroll
        for (int j = 0; j < 16; ++j) s += dot4(w2[j], zp[ln + 64 * j]);
        s = wred(s);
        if (ln == 0) st_dev(h2g + r0, tanhf(s + b2r));
      }
      gbar(bar, ph); ph++;

      // ---------- stage C: k_e = W3 * h2 + b3 (4 owned comps); pre-combine
      // next eval's zin (or final y update + traj at e==5)
#pragma unroll
      for (int m = 0; m < 4; ++m)
        lds_v[tid + 1024 * m] = ld_dev(h2g + tid + 1024 * m);
      __syncthreads();
      {
        int q  = wv >> 2;               // owned row 0..3
        int kq = wv & 3;                // K-quarter
        const float4* wp = (const float4*)w3s + q * 1024 + kq * 256;
        const float4* zp = (const float4*)lds_v + kq * 256;
        float s = 0.f;
#pragma unroll
        for (int j = 0; j < 4; ++j) s += dot4(wp[ln + 64 * j], zp[ln + 64 * j]);
        s = wred(s);
        if (ln == 0) lds_part[q][kq] = s;
      }
      __syncthreads();
      if (tid < 4) {
        int c = bid * 4 + tid;
        float kv = lds_part[tid][0] + lds_part[tid][1] + lds_part[tid][2] +
                   lds_part[tid][3] + b3[c];
        kh[e][tid] = kv;
        float z;
        if (e < 5) {
          // zin_{e+1} = y + dt * sum_{j<=e} A[e+1][j] * k_j
          float acc = 0.f;
          for (int j = 0; j <= e; ++j) acc += c_A[e + 1][j] * kh[j][tid];
          z = ylds[tid] + dt * acc;
        } else {
          float acc = c_B[0] * kh[0][tid] + c_B[1] * kh[1][tid]
                    + c_B[2] * kh[2][tid] + c_B[3] * kh[3][tid]
                    + c_B[4] * kh[4][tid] + c_B[5] * kv;
          z = ylds[tid] + dt * acc;     // y_{n+1}; also eval-0 input of step n+1
          ylds[tid] = z;
          traj[(size_t)n * 1024 + c] = z;
        }
        st_dev(zin + c, z);
      }
      gbar(bar, ph); ph++;
    }
  }
}

extern "C" void kernel_launch(void* const* d_in, const int* in_sizes, int n_in,
                              void* d_out, int out_size, void* d_ws, size_t ws_size,
                              hipStream_t stream) {
  const float* z0 = (const float*)d_in[0];
  const float* W1 = (const float*)d_in[1];
  const float* b1 = (const float*)d_in[2];
  const float* W2 = (const float*)d_in[3];
  const float* b2 = (const float*)d_in[4];
  const float* W3 = (const float*)d_in[5];
  const float* b3 = (const float*)d_in[6];
  const int* t0 = (const int*)d_in[7];
  const int* t1 = (const int*)d_in[8];
  const int* ns = (const int*)d_in[9];
  float* traj = (float*)d_out;

  // barrier counters/flags are monotonic — must start at 0 every launch
  hipMemsetAsync(d_ws, 0, 8192, stream);
  ode_kernel<<<NB, NT, 0, stream>>>(z0, W1, b1, W2, b2, W3, b3, t0, t1, ns,
                                    traj, (float*)d_ws);
}